// Round 6
// baseline (222.947 us; speedup 1.0000x reference)
//
#include <hip/hip_runtime.h>
#include <hip/hip_bf16.h>
#include <math.h>

#define Bsz 2
#define Ssz 2048
#define Esz 1024
#define Hsz 16
#define DHsz 64

typedef __bf16 bf16_t;
typedef __attribute__((ext_vector_type(8))) __bf16 bf16x8;
typedef __attribute__((ext_vector_type(4))) float f32x4;

typedef unsigned int u32;
typedef const __attribute__((address_space(1))) u32* gptr_t;
typedef __attribute__((address_space(3))) u32* lptr_t;

#if __has_builtin(__builtin_amdgcn_exp2f)
#define EXP2F(x) __builtin_amdgcn_exp2f(x)
#else
#define EXP2F(x) __expf((x)*0.69314718f)
#endif

__device__ __forceinline__ bf16_t to_bf16(float f) {
  union { float f; unsigned u; } v; v.f = f;
  unsigned r = (v.u + 0x7FFF + ((v.u >> 16) & 1)) >> 16;   // RNE
  union { unsigned short s; bf16_t b; } o; o.s = (unsigned short)r;
  return o.b;
}

// pack two floats to bf16x2 (RTZ) in ONE v_perm_b32 (consistent P in num+denom)
__device__ __forceinline__ unsigned pack2_rtz(float a, float b) {
#if __has_builtin(__builtin_amdgcn_perm)
  return __builtin_amdgcn_perm(__float_as_uint(b), __float_as_uint(a), 0x07060302u);
#else
  return (__float_as_uint(a) >> 16) | (__float_as_uint(b) & 0xFFFF0000u);
#endif
}

__device__ __forceinline__ unsigned pack2(float a, float b) {
  union { float f; unsigned u; } x, y; x.f = a; y.f = b;
  unsigned ra = (x.u + 0x7FFF + ((x.u >> 16) & 1)) >> 16;
  unsigned rb = (y.u + 0x7FFF + ((y.u >> 16) & 1)) >> 16;
  return ra | (rb << 16);
}

__device__ __forceinline__ f32x4 mfma16(bf16x8 a, bf16x8 b, f32x4 c) {
  return __builtin_amdgcn_mfma_f32_16x16x32_bf16(a, b, c, 0, 0, 0);
}

// async global->LDS, 16B per lane; lds base must be wave-uniform
__device__ __forceinline__ void gload16(void* lds, const void* g) {
  __builtin_amdgcn_global_load_lds((gptr_t)g, (lptr_t)lds, 16, 0, 0);
}

// ---------------- fused prep kernel ----------------
#define PREP_CAST 4096
#define PREP_MASK 4112
__global__ __launch_bounds__(256) void prep(
    const float* __restrict__ x, const int* __restrict__ mask,
    const float* __restrict__ wq, const float* __restrict__ wk,
    const float* __restrict__ wv, const float* __restrict__ wo,
    bf16_t* __restrict__ xb, bf16_t* __restrict__ mb,
    bf16_t* __restrict__ wAll, bf16_t* __restrict__ wAllV, bf16_t* __restrict__ woT) {
  __shared__ bf16_t lT[64 * 72];
  const int bid = blockIdx.x, t = threadIdx.x;
  if (bid < PREP_CAST) {
    const int i = bid * 256 + t;
    float4 v = ((const float4*)x)[i];
    uint2 o; o.x = pack2(v.x, v.y); o.y = pack2(v.z, v.w);
    ((uint2*)xb)[i] = o;
  } else if (bid < PREP_MASK) {
    const int i = (bid - PREP_CAST) * 256 + t;
    mb[i] = to_bf16(mask[i] ? 1.0f : 0.0f);
  } else {
    const int t2 = bid - PREP_MASK;
    const int et = t2 & 15, h = (t2 >> 4) & 15, z = t2 >> 8;
    const float* src; int srcLD; bf16_t* dst;
    if (z == 0)      { src = wq + ((size_t)h * Esz + et * 64) * DHsz; srcLD = DHsz; dst = wAll  + (size_t)(h * 64) * Esz; }
    else if (z == 1) { src = wk + ((size_t)h * Esz + et * 64) * DHsz; srcLD = DHsz; dst = wAll  + (size_t)(1024 + h * 64) * Esz; }
    else if (z == 2) { src = wv + ((size_t)h * Esz + et * 64) * DHsz; srcLD = DHsz; dst = wAllV + (size_t)(h * 64) * Esz; }
    else             { src = wo + (size_t)(et * 64) * Esz + h * 64;   srcLD = Esz;  dst = woT   + (size_t)(h * 64) * Esz; }
#pragma unroll
    for (int rr = 0; rr < 4; rr++) {
      int er = rr * 16 + (t >> 4);
      int dc = (t & 15) * 4;
      float4 v = *(const float4*)&src[(size_t)er * srcLD + dc];
      lT[(dc + 0) * 72 + er] = to_bf16(v.x);
      lT[(dc + 1) * 72 + er] = to_bf16(v.y);
      lT[(dc + 2) * 72 + er] = to_bf16(v.z);
      lT[(dc + 3) * 72 + er] = to_bf16(v.w);
    }
    __syncthreads();
#pragma unroll
    for (int rr = 0; rr < 2; rr++) {
      int d = rr * 32 + (t >> 3);
      int e8 = (t & 7) * 8;
      bf16x8 o = *(const bf16x8*)&lT[d * 72 + e8];
      *(bf16x8*)&dst[(size_t)d * Esz + et * 64 + e8] = o;
    }
  }
}

// ---------------- generic m97-style GEMM core (256 threads) ----------------
template <int TM, int TN>
__device__ __forceinline__ void gemm_core(
    const bf16_t* __restrict__ Ab, const bf16_t* __restrict__ Bb, int K,
    bf16_t* lA, bf16_t* lB, f32x4 (&acc)[TM / 32][TN / 32]) {
  const int tid = threadIdx.x, lane = tid & 63, wvi = tid >> 6;
  const int g = lane >> 4, c = lane & 15, cw = c & 7;
  const int lrow = lane >> 3, sg = lane & 7;
  const int wm = wvi >> 1, wn = wvi & 1;
  for (int kc = 0; kc < K; kc += 64) {
#pragma unroll
    for (int j = 0; j < TM / 32; j++) {
      const int base = (j * 4 + wvi) * 8;
      const int row = base + lrow;
      gload16(lA + base * 64, Ab + (size_t)row * K + kc + ((sg ^ (row & 7)) * 8));
    }
#pragma unroll
    for (int j = 0; j < TN / 32; j++) {
      const int base = (j * 4 + wvi) * 8;
      const int row = base + lrow;
      gload16(lB + base * 64, Bb + (size_t)row * K + kc + ((sg ^ (row & 7)) * 8));
    }
    __syncthreads();
#pragma unroll
    for (int ksp = 0; ksp < 2; ksp++) {
      const int kg = (ksp * 4 + g) ^ cw;
      bf16x8 af[TM / 32], bfr[TN / 32];
#pragma unroll
      for (int mt = 0; mt < TM / 32; mt++)
        af[mt] = *(const bf16x8*)&lA[(wm * (TM / 2) + mt * 16 + c) * 64 + kg * 8];
#pragma unroll
      for (int nt = 0; nt < TN / 32; nt++)
        bfr[nt] = *(const bf16x8*)&lB[(wn * (TN / 2) + nt * 16 + c) * 64 + kg * 8];
#pragma unroll
      for (int mt = 0; mt < TM / 32; mt++)
#pragma unroll
        for (int nt = 0; nt < TN / 32; nt++)
          acc[mt][nt] = mfma16(af[mt], bfr[nt], acc[mt][nt]);
    }
    __syncthreads();
  }
}

// ---------------- fused QKV projection (all 128x128 tiles) ----------------
// blocks [0,512): Q,K GEMM  C = xb[4096x1024].wAll[2048x1024]^T
// blocks [512,768): V^T GEMM  C = wAllV[1024x1024].xb_b[2048x1024]^T (mask folded)
__global__ __launch_bounds__(256, 3) void qkv_gemm(
    const bf16_t* __restrict__ xb, const bf16_t* __restrict__ wAll,
    const bf16_t* __restrict__ wAllV, const bf16_t* __restrict__ mb,
    const float* __restrict__ bq, const float* __restrict__ bk,
    const float* __restrict__ bv,
    bf16_t* __restrict__ qb, bf16_t* __restrict__ kb, bf16_t* __restrict__ vTb) {
  __shared__ alignas(16) bf16_t lA[128 * 64];
  __shared__ alignas(16) bf16_t lB[128 * 64];
  const int bid = blockIdx.x;
  const int lane = threadIdx.x & 63, wvi = threadIdx.x >> 6;
  const int g = lane >> 4, c = lane & 15;
  const int wm = wvi >> 1, wn = wvi & 1;
  f32x4 acc[4][4] = {};
  if (bid < 512) {
    const int Mb = (bid & 31) * 128, Nb = (bid >> 5) * 128;
    gemm_core<128, 128>(xb + (size_t)Mb * Esz, wAll + (size_t)Nb * Esz, Esz, lA, lB, acc);
#pragma unroll
    for (int nt = 0; nt < 4; nt++) {
      const int col = Nb + wn * 64 + nt * 16 + c;
      const int which = col >> 10, h = (col >> 6) & 15, d = col & 63;
      const float bias = (which ? bk : bq)[h * DHsz + d];
      const float scale = which ? 1.0f : 0.18033688011112042f;  // 0.125*log2(e)
      bf16_t* dst = which ? kb : qb;
#pragma unroll
      for (int mt = 0; mt < 4; mt++)
#pragma unroll
        for (int r = 0; r < 4; r++) {
          const int row = Mb + wm * 64 + mt * 16 + g * 4 + r;
          const int b = row >> 11, s = row & 2047;
          dst[(((size_t)(b * Hsz + h)) * Ssz + s) * DHsz + d] =
              to_bf16((acc[mt][nt][r] + bias) * scale);
        }
    }
  } else {
    const int t2 = bid - 512;
    const int Mb = (t2 & 7) * 128, Nb = ((t2 >> 3) & 15) * 128, b = t2 >> 7;
    gemm_core<128, 128>(wAllV + (size_t)Mb * Esz, xb + ((size_t)(b * Ssz) + Nb) * Esz,
                        Esz, lA, lB, acc);
#pragma unroll
    for (int nt = 0; nt < 4; nt++) {
      const int s = Nb + wn * 64 + nt * 16 + c;
      const float mval = (float)mb[b * Ssz + s];   // zero masked V columns
#pragma unroll
      for (int mt = 0; mt < 4; mt++)
#pragma unroll
        for (int r = 0; r < 4; r++) {
          const int m = Mb + wm * 64 + mt * 16 + g * 4 + r;   // = h*64+d
          vTb[((size_t)(b * 1024 + m)) * Ssz + s] = to_bf16((acc[mt][nt][r] + bv[m]) * mval);
        }
    }
  }
}

// ---------------- flash attention: 4 waves = key-split x q-split, 32-key chunks
// grid (H, S/64, B), 256 threads (4 waves).
// wave wv: q-half qh = wv&1 (rows qh*32..), key-half p = wv>>1 (keys p*1024..).
// 32-key chunks (32 iters): lK dbuf 4x4KB=16KB; lP 4x2KB=8KB -> 24KB total.
// K tile DMA'd to LDS double-buffered (stage tc+1 under compute tc); V + mask
// reg-prefetched one chunk ahead. launch_bounds (256,2): R1/R4 proved the 128-reg
// cap of (256,4) forces 64-VGPR + massive scratch spills; live set needs ~170+.
//
// lP layout (R5's stride-40 caused 12.3M bank-conflict cycles ~ 22% of kernel):
// two 32-key P-rows per 128B stripe, 8x16B granule slots XOR-permuted:
//   stripe = qsub*8 + (c>>1)   (128B-aligned -> all stripes start at bank 0)
//   slot   = ((c&1)*4 + kg) ^ ((c>>1)&7)     kg = key granule (8 keys, 16B)
// Per ds_write: each stripe's 8 writer lanes hit 8 distinct 8B slots (balanced
// 4 dwords/bank = min). Per ds_read_b128: each stripe's 8 reader lanes cover all
// 8 slots = all 32 banks exactly once -> hardware-minimum phases, zero conflict.
// Partials combined through LDS at the end (raw exp2, no running max -> pure add).
__global__ __launch_bounds__(256, 2) void flash_attn(
    const bf16_t* __restrict__ qb, const bf16_t* __restrict__ kb,
    const bf16_t* __restrict__ vTb, const bf16_t* __restrict__ mb,
    bf16_t* __restrict__ Ob) {
  // smem map: [0,16KB) lK[p][buf][32*64] ; [16KB,24KB) lP[wv][16*64]
  // after the loop, [0,20KB) is reused as the f32 combine buffer.
  __shared__ alignas(16) char smem[16384 + 4 * 2048];
  bf16_t* lK = (bf16_t*)smem;
  bf16_t* lP = (bf16_t*)(smem + 16384);
  float* cbuf = (float*)smem;

  const int h = blockIdx.x, qt = blockIdx.y, b = blockIdx.z;  // h fastest -> XCD affinity
  const size_t bh = (size_t)(b * Hsz + h);
  const int tid = threadIdx.x, lane = tid & 63, wv = tid >> 6;  // wv in {0,1,2,3}
  const int qh = wv & 1;   // q sub-block
  const int p = wv >> 1;   // key half
  const int g = lane >> 4, c = lane & 15, cw = c & 7;
  const int lrow = lane >> 3, sg = lane & 7;
  const int smask = (c >> 1) & 7;          // lP stripe XOR mask
  const int sbase = (c >> 1) * 64 + (c & 1) * 32;  // stripe base + parity slot-group (bf16 units: slot-group*4*8)

  const bf16_t* Kbase = kb + (bh * Ssz + (size_t)p * 1024) * DHsz;
  const bf16_t* Vlane = vTb + bh * (size_t)DHsz * Ssz + (size_t)c * Ssz + p * 1024 + g * 8;
  const bf16_t* mbb = mb + b * Ssz + p * 1024 + g * 8;
  bf16_t* lKp = lK + p * 2 * 2048;      // this half's two 32x64 K buffers
  bf16_t* lPw = lP + wv * 1024;         // per-wave 16 stripes x 128B = 2KB

  // Q fragments (B-operand), loaded once
  bf16x8 qf[2][2];
  const bf16_t* Qbase = qb + (bh * Ssz + qt * 64 + qh * 32) * DHsz;
#pragma unroll
  for (int qsub = 0; qsub < 2; qsub++)
#pragma unroll
    for (int ksp = 0; ksp < 2; ksp++)
      qf[qsub][ksp] = *(const bf16x8*)&Qbase[(qsub * 16 + c) * DHsz + ksp * 32 + g * 8];

  f32x4 o[2][4] = {};
  f32x4 lac[2] = {};

  // stage this key-half's K chunk (32x64) for chunk tc into lKp[buf]; the two
  // q-waves of the half stage 16 rows each. Swizzled granules (sg ^ row&7).
  auto stage = [&](int tc, int buf) {
#pragma unroll
    for (int j = 0; j < 2; j++) {
      const int rowbase = qh * 16 + j * 8;
      const int row = rowbase + lrow;
      gload16(&lKp[buf * 2048 + rowbase * 64],
              Kbase + ((size_t)(tc * 32 + row)) * DHsz + (sg ^ lrow) * 8);
    }
  };

  auto loadVM = [&](int tc, bf16x8 (&vf)[4], bf16x8& mfr) {
    const bf16_t* vp = Vlane + tc * 32;
    mfr = *(const bf16x8*)&mbb[tc * 32];
#pragma unroll
    for (int dt = 0; dt < 4; dt++)
      vf[dt] = *(const bf16x8*)&vp[dt * 16 * Ssz];
  };

  auto compute = [&](int buf, bf16x8 (&vf)[4], bf16x8& mfr) {
    const bf16_t* Kt = lKp + buf * 2048;
    f32x4 st[2][2] = {};
#pragma unroll
    for (int ksp = 0; ksp < 2; ksp++) {
      const int kgr = (ksp * 4 + g) ^ cw;
#pragma unroll
      for (int nt = 0; nt < 2; nt++) {
        bf16x8 kf = *(const bf16x8*)&Kt[(nt * 16 + c) * 64 + kgr * 8];
        st[0][nt] = mfma16(kf, qf[0][ksp], st[0][nt]);
        st[1][nt] = mfma16(kf, qf[1][ksp], st[1][nt]);
      }
    }
    // exp2 + RTZ pack -> per-wave lP (C-layout -> A-layout round trip)
    // write slot = ((c&1)*4 + nt*2 + (g>>1)) ^ smask, half = g&1 (8B uint2)
#pragma unroll
    for (int qsub = 0; qsub < 2; qsub++)
#pragma unroll
      for (int nt = 0; nt < 2; nt++) {
        float p0 = EXP2F(st[qsub][nt][0]);
        float p1 = EXP2F(st[qsub][nt][1]);
        float p2 = EXP2F(st[qsub][nt][2]);
        float p3 = EXP2F(st[qsub][nt][3]);
        const int slot = (((c & 1) * 4) + nt * 2 + (g >> 1)) ^ smask;
        uint2 pv; pv.x = pack2_rtz(p0, p1); pv.y = pack2_rtz(p2, p3);
        *(uint2*)&lPw[qsub * 512 + (c >> 1) * 64 + slot * 8 + (g & 1) * 4] = pv;
      }
    // PV + l (l via MFMA with mask as B; V pre-masked in qkv_gemm)
    // read slot = ((c&1)*4 + g) ^ smask (16B ds_read_b128, granule kg = g)
    const int slotr = (((c & 1) * 4) + g) ^ smask;
    bf16x8 pf0 = *(const bf16x8*)&lPw[0 * 512 + (c >> 1) * 64 + slotr * 8];
    bf16x8 pf1 = *(const bf16x8*)&lPw[1 * 512 + (c >> 1) * 64 + slotr * 8];
    lac[0] = mfma16(pf0, mfr, lac[0]);
    lac[1] = mfma16(pf1, mfr, lac[1]);
#pragma unroll
    for (int dt = 0; dt < 4; dt++) {
      o[0][dt] = mfma16(pf0, vf[dt], o[0][dt]);
      o[1][dt] = mfma16(pf1, vf[dt], o[1][dt]);
    }
  };

  bf16x8 vA[4], vB[4], mA, mB;
  stage(0, 0);
  loadVM(0, vA, mA);
  __syncthreads();
  for (int tc = 0; tc < 32; tc += 2) {
    // stage/prefetch tc+1 while computing tc
    stage(tc + 1, 1);
    loadVM(tc + 1, vB, mB);
    compute(0, vA, mA);
    __syncthreads();
    if (tc + 2 < 32) {
      stage(tc + 2, 0);
      loadVM(tc + 2, vA, mA);
    }
    compute(1, vB, mB);
    __syncthreads();
  }

  // ---- combine key-halves through LDS (pure add: no running-max rescale) ----
  // (last __syncthreads above guarantees lK/lP reads are done; cbuf aliases them)
  if (p == 1) {
    float* cb = cbuf + ((size_t)(qh * 64 + lane)) * 40;
#pragma unroll
    for (int qsub = 0; qsub < 2; qsub++)
#pragma unroll
      for (int dt = 0; dt < 4; dt++)
        *(f32x4*)&cb[(qsub * 4 + dt) * 4] = o[qsub][dt];
    *(f32x4*)&cb[32] = lac[0];
    *(f32x4*)&cb[36] = lac[1];
  }
  __syncthreads();
  if (p == 0) {
    const float* cb = cbuf + ((size_t)(qh * 64 + lane)) * 40;
#pragma unroll
    for (int qsub = 0; qsub < 2; qsub++)
#pragma unroll
      for (int dt = 0; dt < 4; dt++)
        o[qsub][dt] += *(const f32x4*)&cb[(qsub * 4 + dt) * 4];
    lac[0] += *(const f32x4*)&cb[32];
    lac[1] += *(const f32x4*)&cb[36];

    // epilogue: O row = qsub*16 + g*4 + r, col = dt*16 + c; l in lac[qsub][r]
#pragma unroll
    for (int qsub = 0; qsub < 2; qsub++)
#pragma unroll
      for (int r = 0; r < 4; r++) {
        const int row = qsub * 16 + g * 4 + r;
        const float linv = 1.0f / fmaxf(lac[qsub][r], 1e-30f);
        const size_t orow = (size_t)(b * Ssz + qt * 64 + qh * 32 + row) * Esz + h * DHsz;
#pragma unroll
        for (int dt = 0; dt < 4; dt++)
          Ob[orow + dt * 16 + c] = to_bf16(o[qsub][dt][r] * linv);
      }
  }
}

// ---------------- output projection ----------------
// C = Ob[4096 x 1024] . woT[1024 x 1024]^T + bo, fp32 out. Tiles 128x64.
__global__ __launch_bounds__(256, 3) void out_gemm(
    const bf16_t* __restrict__ Ob, const bf16_t* __restrict__ woT,
    const float* __restrict__ bo, float* __restrict__ out) {
  __shared__ alignas(16) bf16_t lA[128 * 64];
  __shared__ alignas(16) bf16_t lB[64 * 64];
  f32x4 acc[4][2] = {};
  const int Mb = blockIdx.x * 128, Nb = blockIdx.y * 64;
  gemm_core<128, 64>(Ob + (size_t)Mb * Esz, woT + (size_t)Nb * Esz, Esz, lA, lB, acc);
  const int lane = threadIdx.x & 63, wvi = threadIdx.x >> 6;
  const int g = lane >> 4, c = lane & 15;
  const int wm = wvi >> 1, wn = wvi & 1;
#pragma unroll
  for (int nt = 0; nt < 2; nt++) {
    const int col = Nb + wn * 32 + nt * 16 + c;
    const float bias = bo[col];
#pragma unroll
    for (int mt = 0; mt < 4; mt++)
#pragma unroll
      for (int r = 0; r < 4; r++) {
        const int row = Mb + wm * 64 + mt * 16 + g * 4 + r;
        out[(size_t)row * Esz + col] = acc[mt][nt][r] + bias;
      }
  }
}

extern "C" void kernel_launch(void* const* d_in, const int* in_sizes, int n_in,
                              void* d_out, int out_size, void* d_ws, size_t ws_size,
                              hipStream_t stream) {
  const float* x = (const float*)d_in[0];
  const int* mask = (const int*)d_in[1];
  const float* wq = (const float*)d_in[2];
  const float* bq = (const float*)d_in[3];
  const float* wk = (const float*)d_in[4];
  const float* bk = (const float*)d_in[5];
  const float* wv = (const float*)d_in[6];
  const float* bv = (const float*)d_in[7];
  const float* wo = (const float*)d_in[8];
  const float* bo = (const float*)d_in[9];
  float* out = (float*)d_out;

  char* ws = (char*)d_ws;
  size_t off = 0;
  auto take = [&](size_t bytes) -> char* {
    char* p = ws + off;
    off += (bytes + 255) & ~(size_t)255;
    return p;
  };
  bf16_t* xb    = (bf16_t*)take((size_t)Bsz * Ssz * Esz * 2);
  bf16_t* wAll  = (bf16_t*)take((size_t)2 * Esz * Esz * 2);
  bf16_t* wAllV = (bf16_t*)take((size_t)Esz * Esz * 2);
  bf16_t* woT   = (bf16_t*)take((size_t)Esz * Esz * 2);
  bf16_t* qb    = (bf16_t*)take((size_t)Bsz * Hsz * Ssz * DHsz * 2);
  bf16_t* kb    = (bf16_t*)take((size_t)Bsz * Hsz * Ssz * DHsz * 2);
  bf16_t* vTb   = (bf16_t*)take((size_t)Bsz * Hsz * Ssz * DHsz * 2);
  bf16_t* Ob    = (bf16_t*)take((size_t)Bsz * Ssz * Esz * 2);
  bf16_t* mb    = (bf16_t*)take((size_t)Bsz * Ssz * 2);

  prep<<<5136, 256, 0, stream>>>(x, mask, wq, wk, wv, wo, xb, mb, wAll, wAllV, woT);
  qkv_gemm<<<768, 256, 0, stream>>>(xb, wAll, wAllV, mb, bq, bk, bv, qb, kb, vTb);
  flash_attn<<<dim3(Hsz, Ssz / 64, Bsz), 256, 0, stream>>>(qb, kb, vTb, mb, Ob);
  out_gemm<<<dim3(Bsz * Ssz / 128, Esz / 64), 256, 0, stream>>>(Ob, woT, bo, out);
}

// Round 7
// 218.285 us; speedup vs baseline: 1.0214x; 1.0214x over previous
//
#include <hip/hip_runtime.h>
#include <hip/hip_bf16.h>
#include <math.h>

#define Bsz 2
#define Ssz 2048
#define Esz 1024
#define Hsz 16
#define DHsz 64

typedef __bf16 bf16_t;
typedef __attribute__((ext_vector_type(8))) __bf16 bf16x8;
typedef __attribute__((ext_vector_type(4))) float f32x4;

typedef unsigned int u32;
typedef const __attribute__((address_space(1))) u32* gptr_t;
typedef __attribute__((address_space(3))) u32* lptr_t;

#if __has_builtin(__builtin_amdgcn_exp2f)
#define EXP2F(x) __builtin_amdgcn_exp2f(x)
#else
#define EXP2F(x) __expf((x)*0.69314718f)
#endif

// counted vmcnt wait (T4): literal N, memory clobber pins load/ds ordering
#define WAITVMCNT(N) asm volatile("s_waitcnt vmcnt(" #N ")" ::: "memory")
// raw barrier + sched fence (rule #18: stop ds_read hoisting above barrier)
#define BARRIER() do { __builtin_amdgcn_s_barrier(); __builtin_amdgcn_sched_barrier(0); } while (0)

__device__ __forceinline__ bf16_t to_bf16(float f) {
  union { float f; unsigned u; } v; v.f = f;
  unsigned r = (v.u + 0x7FFF + ((v.u >> 16) & 1)) >> 16;   // RNE
  union { unsigned short s; bf16_t b; } o; o.s = (unsigned short)r;
  return o.b;
}

// pack two floats to bf16x2 (RTZ) in ONE v_perm_b32 (consistent P in num+denom)
__device__ __forceinline__ unsigned pack2_rtz(float a, float b) {
#if __has_builtin(__builtin_amdgcn_perm)
  return __builtin_amdgcn_perm(__float_as_uint(b), __float_as_uint(a), 0x07060302u);
#else
  return (__float_as_uint(a) >> 16) | (__float_as_uint(b) & 0xFFFF0000u);
#endif
}

__device__ __forceinline__ unsigned pack2(float a, float b) {
  union { float f; unsigned u; } x, y; x.f = a; y.f = b;
  unsigned ra = (x.u + 0x7FFF + ((x.u >> 16) & 1)) >> 16;
  unsigned rb = (y.u + 0x7FFF + ((y.u >> 16) & 1)) >> 16;
  return ra | (rb << 16);
}

__device__ __forceinline__ f32x4 mfma16(bf16x8 a, bf16x8 b, f32x4 c) {
  return __builtin_amdgcn_mfma_f32_16x16x32_bf16(a, b, c, 0, 0, 0);
}

// async global->LDS, 16B per lane; lds base must be wave-uniform
__device__ __forceinline__ void gload16(void* lds, const void* g) {
  __builtin_amdgcn_global_load_lds((gptr_t)g, (lptr_t)lds, 16, 0, 0);
}

// ---------------- fused prep kernel ----------------
#define PREP_CAST 4096
#define PREP_MASK 4112
__global__ __launch_bounds__(256) void prep(
    const float* __restrict__ x, const int* __restrict__ mask,
    const float* __restrict__ wq, const float* __restrict__ wk,
    const float* __restrict__ wv, const float* __restrict__ wo,
    bf16_t* __restrict__ xb, bf16_t* __restrict__ mb,
    bf16_t* __restrict__ wAll, bf16_t* __restrict__ wAllV, bf16_t* __restrict__ woT) {
  __shared__ bf16_t lT[64 * 72];
  const int bid = blockIdx.x, t = threadIdx.x;
  if (bid < PREP_CAST) {
    const int i = bid * 256 + t;
    float4 v = ((const float4*)x)[i];
    uint2 o; o.x = pack2(v.x, v.y); o.y = pack2(v.z, v.w);
    ((uint2*)xb)[i] = o;
  } else if (bid < PREP_MASK) {
    const int i = (bid - PREP_CAST) * 256 + t;
    mb[i] = to_bf16(mask[i] ? 1.0f : 0.0f);
  } else {
    const int t2 = bid - PREP_MASK;
    const int et = t2 & 15, h = (t2 >> 4) & 15, z = t2 >> 8;
    const float* src; int srcLD; bf16_t* dst;
    if (z == 0)      { src = wq + ((size_t)h * Esz + et * 64) * DHsz; srcLD = DHsz; dst = wAll  + (size_t)(h * 64) * Esz; }
    else if (z == 1) { src = wk + ((size_t)h * Esz + et * 64) * DHsz; srcLD = DHsz; dst = wAll  + (size_t)(1024 + h * 64) * Esz; }
    else if (z == 2) { src = wv + ((size_t)h * Esz + et * 64) * DHsz; srcLD = DHsz; dst = wAllV + (size_t)(h * 64) * Esz; }
    else             { src = wo + (size_t)(et * 64) * Esz + h * 64;   srcLD = Esz;  dst = woT   + (size_t)(h * 64) * Esz; }
#pragma unroll
    for (int rr = 0; rr < 4; rr++) {
      int er = rr * 16 + (t >> 4);
      int dc = (t & 15) * 4;
      float4 v = *(const float4*)&src[(size_t)er * srcLD + dc];
      lT[(dc + 0) * 72 + er] = to_bf16(v.x);
      lT[(dc + 1) * 72 + er] = to_bf16(v.y);
      lT[(dc + 2) * 72 + er] = to_bf16(v.z);
      lT[(dc + 3) * 72 + er] = to_bf16(v.w);
    }
    __syncthreads();
#pragma unroll
    for (int rr = 0; rr < 2; rr++) {
      int d = rr * 32 + (t >> 3);
      int e8 = (t & 7) * 8;
      bf16x8 o = *(const bf16x8*)&lT[d * 72 + e8];
      *(bf16x8*)&dst[(size_t)d * Esz + et * 64 + e8] = o;
    }
  }
}

// ---------------- generic m97-style GEMM core (256 threads) ----------------
template <int TM, int TN>
__device__ __forceinline__ void gemm_core(
    const bf16_t* __restrict__ Ab, const bf16_t* __restrict__ Bb, int K,
    bf16_t* lA, bf16_t* lB, f32x4 (&acc)[TM / 32][TN / 32]) {
  const int tid = threadIdx.x, lane = tid & 63, wvi = tid >> 6;
  const int g = lane >> 4, c = lane & 15, cw = c & 7;
  const int lrow = lane >> 3, sg = lane & 7;
  const int wm = wvi >> 1, wn = wvi & 1;
  for (int kc = 0; kc < K; kc += 64) {
#pragma unroll
    for (int j = 0; j < TM / 32; j++) {
      const int base = (j * 4 + wvi) * 8;
      const int row = base + lrow;
      gload16(lA + base * 64, Ab + (size_t)row * K + kc + ((sg ^ (row & 7)) * 8));
    }
#pragma unroll
    for (int j = 0; j < TN / 32; j++) {
      const int base = (j * 4 + wvi) * 8;
      const int row = base + lrow;
      gload16(lB + base * 64, Bb + (size_t)row * K + kc + ((sg ^ (row & 7)) * 8));
    }
    __syncthreads();
#pragma unroll
    for (int ksp = 0; ksp < 2; ksp++) {
      const int kg = (ksp * 4 + g) ^ cw;
      bf16x8 af[TM / 32], bfr[TN / 32];
#pragma unroll
      for (int mt = 0; mt < TM / 32; mt++)
        af[mt] = *(const bf16x8*)&lA[(wm * (TM / 2) + mt * 16 + c) * 64 + kg * 8];
#pragma unroll
      for (int nt = 0; nt < TN / 32; nt++)
        bfr[nt] = *(const bf16x8*)&lB[(wn * (TN / 2) + nt * 16 + c) * 64 + kg * 8];
#pragma unroll
      for (int mt = 0; mt < TM / 32; mt++)
#pragma unroll
        for (int nt = 0; nt < TN / 32; nt++)
          acc[mt][nt] = mfma16(af[mt], bfr[nt], acc[mt][nt]);
    }
    __syncthreads();
  }
}

// ---------------- fused QKV projection (all 128x128 tiles) ----------------
// blocks [0,512): Q,K GEMM  C = xb[4096x1024].wAll[2048x1024]^T
// blocks [512,768): V^T GEMM  C = wAllV[1024x1024].xb_b[2048x1024]^T (mask folded)
__global__ __launch_bounds__(256, 3) void qkv_gemm(
    const bf16_t* __restrict__ xb, const bf16_t* __restrict__ wAll,
    const bf16_t* __restrict__ wAllV, const bf16_t* __restrict__ mb,
    const float* __restrict__ bq, const float* __restrict__ bk,
    const float* __restrict__ bv,
    bf16_t* __restrict__ qb, bf16_t* __restrict__ kb, bf16_t* __restrict__ vTb) {
  __shared__ alignas(16) bf16_t lA[128 * 64];
  __shared__ alignas(16) bf16_t lB[128 * 64];
  const int bid = blockIdx.x;
  const int lane = threadIdx.x & 63, wvi = threadIdx.x >> 6;
  const int g = lane >> 4, c = lane & 15;
  const int wm = wvi >> 1, wn = wvi & 1;
  f32x4 acc[4][4] = {};
  if (bid < 512) {
    const int Mb = (bid & 31) * 128, Nb = (bid >> 5) * 128;
    gemm_core<128, 128>(xb + (size_t)Mb * Esz, wAll + (size_t)Nb * Esz, Esz, lA, lB, acc);
#pragma unroll
    for (int nt = 0; nt < 4; nt++) {
      const int col = Nb + wn * 64 + nt * 16 + c;
      const int which = col >> 10, h = (col >> 6) & 15, d = col & 63;
      const float bias = (which ? bk : bq)[h * DHsz + d];
      const float scale = which ? 1.0f : 0.18033688011112042f;  // 0.125*log2(e)
      bf16_t* dst = which ? kb : qb;
#pragma unroll
      for (int mt = 0; mt < 4; mt++)
#pragma unroll
        for (int r = 0; r < 4; r++) {
          const int row = Mb + wm * 64 + mt * 16 + g * 4 + r;
          const int b = row >> 11, s = row & 2047;
          dst[(((size_t)(b * Hsz + h)) * Ssz + s) * DHsz + d] =
              to_bf16((acc[mt][nt][r] + bias) * scale);
        }
    }
  } else {
    const int t2 = bid - 512;
    const int Mb = (t2 & 7) * 128, Nb = ((t2 >> 3) & 15) * 128, b = t2 >> 7;
    gemm_core<128, 128>(wAllV + (size_t)Mb * Esz, xb + ((size_t)(b * Ssz) + Nb) * Esz,
                        Esz, lA, lB, acc);
#pragma unroll
    for (int nt = 0; nt < 4; nt++) {
      const int s = Nb + wn * 64 + nt * 16 + c;
      const float mval = (float)mb[b * Ssz + s];   // zero masked V columns
#pragma unroll
      for (int mt = 0; mt < 4; mt++)
#pragma unroll
        for (int r = 0; r < 4; r++) {
          const int m = Mb + wm * 64 + mt * 16 + g * 4 + r;   // = h*64+d
          vTb[((size_t)(b * 1024 + m)) * Ssz + s] = to_bf16((acc[mt][nt][r] + bv[m]) * mval);
        }
    }
  }
}

// ---------------- flash attention: 4 waves = key-split x q-split, 32-key chunks
// grid (H, S/64, B), 256 threads (4 waves).
// wave wv: q-half qh = wv&1 (rows qh*32..), key-half p = wv>>1 (keys p*1024..).
//
// R6 localization: with __syncthreads per chunk, the barrier's vmcnt(0) drain
// waited on stage/V loads issued only ~1 compute phase (~250cy) earlier ->
// ~600-900cy L3/HBM latency exposed EVERY chunk (MfmaUtil 17%, stall ~60%).
// T3/T4 fix: 2-chunk-deep pipeline with counted vmcnt, never 0 in the loop.
//   K: 4 LDS buffers/half (b0..b3, chunk t -> buf t%4, static idx).
//   per chunk: 2 gload_lds (K) + 5 global (4 V + 1 mask) = 7 VMEM ops.
//   schedule: compute(t); issue S/V(t+2); s_waitcnt vmcnt(7)  [drains t+1's 7,
//   leaves t+2's 7 in flight]; s_barrier. Buffer overwritten by S(t+2) was last
//   read at compute(t-2), >=2 barriers ago -> no DMA race.
// LDS: lK 2 halves x 4 bufs x 4KB = 32KB + lP 8KB = 40KB; 4 blocks x 40KB =
// 160KB exact -> residency still reg-capped (2 blocks/CU), unchanged.
// launch_bounds (256,2): R1/R4 proved smaller caps force 64-VGPR + spills
// (spills would also break the vmcnt ledger - scratch ops count in vmcnt).
// lP layout: R6's conflict-free stripe/slot XOR scheme (conflicts 12.3M->2.3M).
// Partials combined through LDS at the end (raw exp2, no running max -> pure add).
__global__ __launch_bounds__(256, 2) void flash_attn(
    const bf16_t* __restrict__ qb, const bf16_t* __restrict__ kb,
    const bf16_t* __restrict__ vTb, const bf16_t* __restrict__ mb,
    bf16_t* __restrict__ Ob) {
  // smem map: [0,32KB) lK[p][buf0..3][32*64] ; [32KB,40KB) lP[wv][16*64]
  // after the loop, [0,20KB) is reused as the f32 combine buffer.
  __shared__ alignas(16) char smem[32768 + 4 * 2048];
  bf16_t* lK = (bf16_t*)smem;
  bf16_t* lP = (bf16_t*)(smem + 32768);
  float* cbuf = (float*)smem;

  const int h = blockIdx.x, qt = blockIdx.y, b = blockIdx.z;  // h fastest -> XCD affinity
  const size_t bh = (size_t)(b * Hsz + h);
  const int tid = threadIdx.x, lane = tid & 63, wv = tid >> 6;  // wv in {0,1,2,3}
  const int qh = wv & 1;   // q sub-block
  const int p = wv >> 1;   // key half
  const int g = lane >> 4, c = lane & 15, cw = c & 7;
  const int lrow = lane >> 3, sg = lane & 7;
  const int smask = (c >> 1) & 7;          // lP stripe XOR mask

  const bf16_t* Kbase = kb + (bh * Ssz + (size_t)p * 1024) * DHsz;
  const bf16_t* Vlane = vTb + bh * (size_t)DHsz * Ssz + (size_t)c * Ssz + p * 1024 + g * 8;
  const bf16_t* mbb = mb + b * Ssz + p * 1024 + g * 8;
  bf16_t* lKp = lK + p * 4 * 2048;      // this half's four 32x64 K buffers
  bf16_t* lPw = lP + wv * 1024;         // per-wave 16 stripes x 128B = 2KB

  // Q fragments (B-operand), loaded once
  bf16x8 qf[2][2];
  const bf16_t* Qbase = qb + (bh * Ssz + qt * 64 + qh * 32) * DHsz;
#pragma unroll
  for (int qsub = 0; qsub < 2; qsub++)
#pragma unroll
    for (int ksp = 0; ksp < 2; ksp++)
      qf[qsub][ksp] = *(const bf16x8*)&Qbase[(qsub * 16 + c) * DHsz + ksp * 32 + g * 8];

  f32x4 o[2][4] = {};
  f32x4 lac[2] = {};

  // stage this key-half's K chunk (32x64) for chunk tc into lKp buf (static idx);
  // the two q-waves of the half stage 16 rows each. Swizzled granules (sg^lrow).
  auto stage = [&](int tc, int buf) {
#pragma unroll
    for (int j = 0; j < 2; j++) {
      const int rowbase = qh * 16 + j * 8;
      const int row = rowbase + lrow;
      gload16(&lKp[buf * 2048 + rowbase * 64],
              Kbase + ((size_t)(tc * 32 + row)) * DHsz + (sg ^ lrow) * 8);
    }
  };

  auto loadVM = [&](int tc, bf16x8 (&vf)[4], bf16x8& mfr) {
    const bf16_t* vp = Vlane + tc * 32;
    mfr = *(const bf16x8*)&mbb[tc * 32];
#pragma unroll
    for (int dt = 0; dt < 4; dt++)
      vf[dt] = *(const bf16x8*)&vp[dt * 16 * Ssz];
  };

  auto compute = [&](int buf, bf16x8 (&vf)[4], bf16x8& mfr) {
    const bf16_t* Kt = lKp + buf * 2048;
    f32x4 st[2][2] = {};
#pragma unroll
    for (int ksp = 0; ksp < 2; ksp++) {
      const int kgr = (ksp * 4 + g) ^ cw;
#pragma unroll
      for (int nt = 0; nt < 2; nt++) {
        bf16x8 kf = *(const bf16x8*)&Kt[(nt * 16 + c) * 64 + kgr * 8];
        st[0][nt] = mfma16(kf, qf[0][ksp], st[0][nt]);
        st[1][nt] = mfma16(kf, qf[1][ksp], st[1][nt]);
      }
    }
    // exp2 + RTZ pack -> per-wave lP (C-layout -> A-layout round trip)
    // write slot = ((c&1)*4 + nt*2 + (g>>1)) ^ smask, half = g&1 (8B uint2)
#pragma unroll
    for (int qsub = 0; qsub < 2; qsub++)
#pragma unroll
      for (int nt = 0; nt < 2; nt++) {
        float p0 = EXP2F(st[qsub][nt][0]);
        float p1 = EXP2F(st[qsub][nt][1]);
        float p2 = EXP2F(st[qsub][nt][2]);
        float p3 = EXP2F(st[qsub][nt][3]);
        const int slot = (((c & 1) * 4) + nt * 2 + (g >> 1)) ^ smask;
        uint2 pv; pv.x = pack2_rtz(p0, p1); pv.y = pack2_rtz(p2, p3);
        *(uint2*)&lPw[qsub * 512 + (c >> 1) * 64 + slot * 8 + (g & 1) * 4] = pv;
      }
    // PV + l (l via MFMA with mask as B; V pre-masked in qkv_gemm)
    // read slot = ((c&1)*4 + g) ^ smask (16B ds_read_b128, granule kg = g)
    const int slotr = (((c & 1) * 4) + g) ^ smask;
    bf16x8 pf0 = *(const bf16x8*)&lPw[0 * 512 + (c >> 1) * 64 + slotr * 8];
    bf16x8 pf1 = *(const bf16x8*)&lPw[1 * 512 + (c >> 1) * 64 + slotr * 8];
    lac[0] = mfma16(pf0, mfr, lac[0]);
    lac[1] = mfma16(pf1, mfr, lac[1]);
#pragma unroll
    for (int dt = 0; dt < 4; dt++) {
      o[0][dt] = mfma16(pf0, vf[dt], o[0][dt]);
      o[1][dt] = mfma16(pf1, vf[dt], o[1][dt]);
    }
  };

  bf16x8 vA[4], vB[4], mA, mB;
  // prologue: issue chunks 0 and 1 (7 VMEM ops each; Q loads may also be in
  // flight -- vmcnt(7) below drains Q + chunk0, leaves chunk1's 7 outstanding)
  stage(0, 0); loadVM(0, vA, mA);
  stage(1, 1); loadVM(1, vB, mB);
  WAITVMCNT(7); BARRIER();               // chunk0 ready (all waves)
  // steady state: 28 chunks, full 2-deep pipeline, vmcnt never drained to 0
  for (int tc = 0; tc < 28; tc += 4) {
    compute(0, vA, mA);                                    // chunk tc+0
    stage(tc + 2, 2); loadVM(tc + 2, vA, mA); WAITVMCNT(7); BARRIER();
    compute(1, vB, mB);                                    // chunk tc+1
    stage(tc + 3, 3); loadVM(tc + 3, vB, mB); WAITVMCNT(7); BARRIER();
    compute(2, vA, mA);                                    // chunk tc+2
    stage(tc + 4, 0); loadVM(tc + 4, vA, mA); WAITVMCNT(7); BARRIER();
    compute(3, vB, mB);                                    // chunk tc+3
    stage(tc + 5, 1); loadVM(tc + 5, vB, mB); WAITVMCNT(7); BARRIER();
  }
  // tail: chunks 28..31 in bufs 0..3 (chunk 29 already in flight)
  compute(0, vA, mA);                                      // chunk 28
  stage(30, 2); loadVM(30, vA, mA); WAITVMCNT(7); BARRIER();
  compute(1, vB, mB);                                      // chunk 29
  stage(31, 3); loadVM(31, vB, mB); WAITVMCNT(7); BARRIER();
  compute(2, vA, mA);                                      // chunk 30
  WAITVMCNT(0); BARRIER();
  compute(3, vB, mB);                                      // chunk 31

  // ---- combine key-halves through LDS (pure add: no running-max rescale) ----
  __syncthreads();   // all lK/lP reads done before cbuf alias writes
  if (p == 1) {
    float* cb = cbuf + ((size_t)(qh * 64 + lane)) * 40;
#pragma unroll
    for (int qsub = 0; qsub < 2; qsub++)
#pragma unroll
      for (int dt = 0; dt < 4; dt++)
        *(f32x4*)&cb[(qsub * 4 + dt) * 4] = o[qsub][dt];
    *(f32x4*)&cb[32] = lac[0];
    *(f32x4*)&cb[36] = lac[1];
  }
  __syncthreads();
  if (p == 0) {
    const float* cb = cbuf + ((size_t)(qh * 64 + lane)) * 40;
#pragma unroll
    for (int qsub = 0; qsub < 2; qsub++)
#pragma unroll
      for (int dt = 0; dt < 4; dt++)
        o[qsub][dt] += *(const f32x4*)&cb[(qsub * 4 + dt) * 4];
    lac[0] += *(const f32x4*)&cb[32];
    lac[1] += *(const f32x4*)&cb[36];

    // epilogue: O row = qsub*16 + g*4 + r, col = dt*16 + c; l in lac[qsub][r]
#pragma unroll
    for (int qsub = 0; qsub < 2; qsub++)
#pragma unroll
      for (int r = 0; r < 4; r++) {
        const int row = qsub * 16 + g * 4 + r;
        const float linv = 1.0f / fmaxf(lac[qsub][r], 1e-30f);
        const size_t orow = (size_t)(b * Ssz + qt * 64 + qh * 32 + row) * Esz + h * DHsz;
#pragma unroll
        for (int dt = 0; dt < 4; dt++)
          Ob[orow + dt * 16 + c] = to_bf16(o[qsub][dt][r] * linv);
      }
  }
}

// ---------------- output projection ----------------
// C = Ob[4096 x 1024] . woT[1024 x 1024]^T + bo, fp32 out. Tiles 128x64.
__global__ __launch_bounds__(256, 3) void out_gemm(
    const bf16_t* __restrict__ Ob, const bf16_t* __restrict__ woT,
    const float* __restrict__ bo, float* __restrict__ out) {
  __shared__ alignas(16) bf16_t lA[128 * 64];
  __shared__ alignas(16) bf16_t lB[64 * 64];
  f32x4 acc[4][2] = {};
  const int Mb = blockIdx.x * 128, Nb = blockIdx.y * 64;
  gemm_core<128, 64>(Ob + (size_t)Mb * Esz, woT + (size_t)Nb * Esz, Esz, lA, lB, acc);
  const int lane = threadIdx.x & 63, wvi = threadIdx.x >> 6;
  const int g = lane >> 4, c = lane & 15;
  const int wm = wvi >> 1, wn = wvi & 1;
#pragma unroll
  for (int nt = 0; nt < 2; nt++) {
    const int col = Nb + wn * 32 + nt * 16 + c;
    const float bias = bo[col];
#pragma unroll
    for (int mt = 0; mt < 4; mt++)
#pragma unroll
      for (int r = 0; r < 4; r++) {
        const int row = Mb + wm * 64 + mt * 16 + g * 4 + r;
        out[(size_t)row * Esz + col] = acc[mt][nt][r] + bias;
      }
  }
}

extern "C" void kernel_launch(void* const* d_in, const int* in_sizes, int n_in,
                              void* d_out, int out_size, void* d_ws, size_t ws_size,
                              hipStream_t stream) {
  const float* x = (const float*)d_in[0];
  const int* mask = (const int*)d_in[1];
  const float* wq = (const float*)d_in[2];
  const float* bq = (const float*)d_in[3];
  const float* wk = (const float*)d_in[4];
  const float* bk = (const float*)d_in[5];
  const float* wv = (const float*)d_in[6];
  const float* bv = (const float*)d_in[7];
  const float* wo = (const float*)d_in[8];
  const float* bo = (const float*)d_in[9];
  float* out = (float*)d_out;

  char* ws = (char*)d_ws;
  size_t off = 0;
  auto take = [&](size_t bytes) -> char* {
    char* p = ws + off;
    off += (bytes + 255) & ~(size_t)255;
    return p;
  };
  bf16_t* xb    = (bf16_t*)take((size_t)Bsz * Ssz * Esz * 2);
  bf16_t* wAll  = (bf16_t*)take((size_t)2 * Esz * Esz * 2);
  bf16_t* wAllV = (bf16_t*)take((size_t)Esz * Esz * 2);
  bf16_t* woT   = (bf16_t*)take((size_t)Esz * Esz * 2);
  bf16_t* qb    = (bf16_t*)take((size_t)Bsz * Hsz * Ssz * DHsz * 2);
  bf16_t* kb    = (bf16_t*)take((size_t)Bsz * Hsz * Ssz * DHsz * 2);
  bf16_t* vTb   = (bf16_t*)take((size_t)Bsz * Hsz * Ssz * DHsz * 2);
  bf16_t* Ob    = (bf16_t*)take((size_t)Bsz * Ssz * Esz * 2);
  bf16_t* mb    = (bf16_t*)take((size_t)Bsz * Ssz * 2);

  prep<<<5136, 256, 0, stream>>>(x, mask, wq, wk, wv, wo, xb, mb, wAll, wAllV, woT);
  qkv_gemm<<<768, 256, 0, stream>>>(xb, wAll, wAllV, mb, bq, bk, bv, qb, kb, vTb);
  flash_attn<<<dim3(Hsz, Ssz / 64, Bsz), 256, 0, stream>>>(qb, kb, vTb, mb, Ob);
  out_gemm<<<dim3(Bsz * Ssz / 128, Esz / 64), 256, 0, stream>>>(Ob, woT, bo, out);
}